// Round 15
// baseline (128.578 us; speedup 1.0000x reference)
//
#include <hip/hip_runtime.h>

#define Bn 8
#define Sn 4096
#define Dn 64

constexpr int NKT = Sn / 64;    // 64 k-tiles per batch
constexpr int NQT = Sn / 128;   // 32 q-tiles per batch (linv q-sweep)

typedef _Float16 half_t;
typedef __attribute__((ext_vector_type(2))) _Float16 half2v;
typedef __attribute__((ext_vector_type(4))) _Float16 half4;
typedef __attribute__((ext_vector_type(8))) _Float16 half8;
typedef __attribute__((ext_vector_type(4))) float f32x4;

constexpr float SCALE = 0.125f;                         // fallback path
constexpr float SCALE2 = 0.125f * 1.4426950408889634f;  // fold log2e -> exp2

#define MFMA32(a, b, c) __builtin_amdgcn_mfma_f32_16x16x32_f16((a), (b), (c), 0, 0, 0)
#define MFMA16(a, b, c) __builtin_amdgcn_mfma_f32_16x16x16f16((a), (b), (c), 0, 0, 0)

// Raw v_exp_f32 (args bounded; libm denorm fixup is dead weight).
__device__ __forceinline__ float fexp2(float x) {
#if defined(__has_builtin) && __has_builtin(__builtin_amdgcn_exp2f)
  return __builtin_amdgcn_exp2f(x);
#else
  return exp2f(x);
#endif
}

// Swizzled half-index for row-major [R][64] f16 tiles.
__device__ __forceinline__ int swz_k(int row, int col) {
  return row * 64 + (col ^ ((row & 7) << 3));
}
__device__ __forceinline__ int swz_v(int row, int col) {
  return row * 64 + (col ^ (((row & 7) << 3) ^ (((row >> 3) & 7) << 2)));
}

// f32 -> f16 hi + f16 lo (x ~= h + l, err ~2^-22|x|)
__device__ __forceinline__ void cvt8(const float* s, half8& h, half8& l) {
  #pragma unroll
  for (int j = 0; j < 8; ++j) {
    half_t hh = (half_t)s[j];
    h[j] = hh;
    l[j] = (half_t)(s[j] - (float)hh);
  }
}

// Async global->LDS 16B per lane: lds base must be wave-uniform.
__device__ __forceinline__ void cp16(half_t* lds, const half_t* g) {
  __builtin_amdgcn_global_load_lds(
      (const __attribute__((address_space(1))) unsigned int*)g,
      (__attribute__((address_space(3))) unsigned int*)lds, 16, 0, 0);
}

// ===========================================================================
// FAST PATH (needs ~21 MB of d_ws)
// ws layout: li (128KB @0) | QhW (4MB @1MB) | QlW (4MB @5MB) | KVW (8MB @9MB)
// KVW per k-tile blob (8192 halfs): [0,4096) Kh (swz_k) | [4096,8192) Vt (swz_v)
// 2-term QK (kh*qh + kh*ql) in BOTH linv and pv: normalization exact w.r.t.
// the shared approximation s^ = q . f16(K) (validated round 14: absmax
// unchanged at 9.77e-4).
// ===========================================================================

// ---------------------------------------------------------------------------
// prep_q: Q (f32) -> QhW/QlW (f16 hi/lo, scaled by SCALE2, swz_k layout).
// ---------------------------------------------------------------------------
__global__ __launch_bounds__(256, 2)
void prep_q(const float* __restrict__ Qg, half_t* __restrict__ QhW,
            half_t* __restrict__ QlW) {
  const int t = threadIdx.x;
  const int b = blockIdx.x & 7, qt = blockIdx.x >> 3;
  const float* Qb = Qg + ((size_t)(b * Sn + qt * 128)) * Dn;
  half_t* qh = QhW + ((size_t)(b * NQT + qt)) * 8192;
  half_t* ql = QlW + ((size_t)(b * NQT + qt)) * 8192;
  #pragma unroll
  for (int i = 0; i < 8; ++i) {
    int f = t + 256 * i, q = f >> 4, d4 = (f & 15) << 2;
    float4 v = *(const float4*)(Qb + (size_t)q * Dn + d4);
    float s4[4] = {v.x * SCALE2, v.y * SCALE2, v.z * SCALE2, v.w * SCALE2};
    half4 h, l;
    #pragma unroll
    for (int j = 0; j < 4; ++j) {
      half_t hh = (half_t)s4[j];
      h[j] = hh;
      l[j] = (half_t)(s4[j] - (float)hh);
    }
    *(half4*)&qh[swz_k(q, d4)] = h;
    *(half4*)&ql[swz_k(q, d4)] = l;
  }
}

// ---------------------------------------------------------------------------
// attn_linv: lg2inv[b,k] = -log2(sum_q exp2(s^'[q,k])) + fused K/V prep into
// the KVW blob (Kh + Vt only). 256 thr / (256,2). Rule #20: prep write uses
// compile-time `if (ks == w)` indexing (runtime kfh[w] -> scratch, 5x).
// ---------------------------------------------------------------------------
__global__ __launch_bounds__(256, 2)
void attn_linv(const float* __restrict__ Kg, const float* __restrict__ Vg,
               const half_t* __restrict__ QhW, const half_t* __restrict__ QlW,
               float* __restrict__ lg2inv, half_t* __restrict__ KVW) {
  __shared__ alignas(16) half_t Qh_s[2][8192];   // 2 x 16KB
  __shared__ alignas(16) half_t Ql_s[2][8192];   // 2 x 16KB
  __shared__ alignas(16) float red[4][4][16];

  const int t = threadIdx.x;
  const int lane = t & 63, w = t >> 6, g = lane >> 4, c16 = lane & 15;
  const int b = blockIdx.x & 7, kx = blockIdx.x >> 3;
  const int k0 = kx * 64;

  half_t* blob = KVW + ((size_t)(b * NKT + kx)) * 8192;

  // --- K hi fragments (registers) + one-time prep write into blob ---
  half8 kfh[4][2];
  #pragma unroll
  for (int ks = 0; ks < 4; ++ks)
    #pragma unroll
    for (int c = 0; c < 2; ++c) {
      const float* src = Kg + ((size_t)(b * Sn + k0 + 16 * ks + c16)) * Dn + 32 * c + 8 * g;
      float a8[8];
      *(float4*)&a8[0] = *(const float4*)src;
      *(float4*)&a8[4] = *(const float4*)(src + 4);
      #pragma unroll
      for (int j = 0; j < 8; ++j) kfh[ks][c][j] = (half_t)a8[j];
    }
  {
    #pragma unroll
    for (int ks = 0; ks < 4; ++ks)
      if (ks == w) {  // compile-time ks index under predication — no scratch
        #pragma unroll
        for (int c = 0; c < 2; ++c)
          *(half8*)&blob[swz_k(16 * ks + c16, 32 * c + 8 * g)] = kfh[ks][c];
      }
  }
  // --- one-time V transpose prep into blob[4096..] ---
  {
    const float* Vb = Vg + ((size_t)(b * Sn + k0)) * Dn;
    #pragma unroll
    for (int i = 0; i < 2; ++i) {
      int u = t + 256 * i;
      int k2 = u >> 4, dg = u & 15;
      float4 v0 = *(const float4*)(Vb + (size_t)(2 * k2) * Dn + 4 * dg);
      float4 v1 = *(const float4*)(Vb + (size_t)(2 * k2 + 1) * Dn + 4 * dg);
      const float* v0p = (const float*)&v0;
      const float* v1p = (const float*)&v1;
      #pragma unroll
      for (int j = 0; j < 4; ++j) {
        half2v pair = {(half_t)v0p[j], (half_t)v1p[j]};
        *(half2v*)&blob[4096 + swz_v(4 * dg + j, 2 * k2)] = pair;
      }
    }
  }

  const half_t* qhw = QhW + (size_t)b * NQT * 8192;
  const half_t* qlw = QlW + (size_t)b * NQT * 8192;

  // DMA one 128-q tile (16KB per array): 4 chunks/wave/array.
  auto load_q = [&](int bb, int qt) {
    const size_t toff = (size_t)qt * 8192;
    #pragma unroll
    for (int c = 0; c < 4; ++c) {
      const int ch = (c * 4 + w) * 512;  // halfs
      cp16(&Qh_s[bb][ch], qhw + toff + ch + lane * 8);
      cp16(&Ql_s[bb][ch], qlw + toff + ch + lane * 8);
    }
  };

  float lsum[4] = {0.f, 0.f, 0.f, 0.f};

  load_q(0, 0);
  __syncthreads();
  for (int qt = 0; qt < NQT; ++qt) {
    if (qt + 1 < NQT) load_q((qt + 1) & 1, qt + 1);
    const int cur = qt & 1;
    #pragma unroll
    for (int qs = 0; qs < 2; ++qs) {
      const int qloc = 32 * w + 16 * qs + c16;
      half8 qh[2], ql[2];
      #pragma unroll
      for (int c = 0; c < 2; ++c) {
        qh[c] = *(const half8*)&Qh_s[cur][swz_k(qloc, 32 * c + 8 * g)];
        ql[c] = *(const half8*)&Ql_s[cur][swz_k(qloc, 32 * c + 8 * g)];
      }
      #pragma unroll
      for (int ks = 0; ks < 4; ++ks) {
        f32x4 acc = {0.f, 0.f, 0.f, 0.f};
        acc = MFMA32(qh[0], kfh[ks][0], acc);
        acc = MFMA32(qh[1], kfh[ks][1], acc);
        acc = MFMA32(ql[0], kfh[ks][0], acc);
        acc = MFMA32(ql[1], kfh[ks][1], acc);
        lsum[ks] += fexp2(acc[0]) + fexp2(acc[1]) + fexp2(acc[2]) + fexp2(acc[3]);
      }
    }
    __syncthreads();
  }

  // lane (c16,g) holds partials for column k = k0+16ks+c16 over its q rows
  #pragma unroll
  for (int ks = 0; ks < 4; ++ks) {
    lsum[ks] += __shfl_xor(lsum[ks], 16);
    lsum[ks] += __shfl_xor(lsum[ks], 32);
  }
  __syncthreads();
  if (lane < 16) {
    #pragma unroll
    for (int ks = 0; ks < 4; ++ks) red[w][ks][lane] = lsum[ks];
  }
  __syncthreads();
  if (t < 64) {
    int ks = t >> 4, c = t & 15;
    float tot = red[0][ks][c] + red[1][ks][c] + red[2][ks][c] + red[3][ks][c];
    lg2inv[(size_t)b * Sn + k0 + 16 * ks + c] = -log2f(tot);
  }
}

// ---------------------------------------------------------------------------
// attn_pv: O[q,d] = sum_k exp2(s^' + lg2inv[k]) * V[k,d].
// q-tile 32, grid 1024 -> 4 blocks/CU (4 independent barrier domains),
// 8 waves/SIMD (max occupancy). Per wave: ONE q fragment (wq = w>>2 in
// {0,1} owns 16 q rows), wk = w&3 owns 1 ks; 4 MFMA32 + 4 MFMA16 + 4 exp
// per tile. Same total work as round 14, finer interleave: de-phased blocks
// cover each other's barrier drains and exp phases. VGPR must stay <= 64
// for (512,8) — watch FETCH for spill evidence (round-7 lesson).
// ---------------------------------------------------------------------------
__global__ __launch_bounds__(512, 8)
void attn_pv(const half_t* __restrict__ KVW, const float* __restrict__ Qg,
             const float* __restrict__ lg2inv, float* __restrict__ Og) {
  __shared__ alignas(16) half_t KV_s[2][8192];  // [Kh 8KB | Vt 8KB] per buffer

  const int t = threadIdx.x;
  const int lane = t & 63, w = t >> 6;  // 8 waves
  const int g = (lane >> 4) & 3, c16 = lane & 15;
  const int wk = w & 3, wq = w >> 2;    // wq in {0,1}
  const int b = blockIdx.x & 7;
  const int q0 = (blockIdx.x >> 3) * 32;
  const int qrow = q0 + 16 * wq + c16;

  // Resident Q fragment (hi/lo, scaled by SCALE2), one-time from global.
  half8 qh[2], ql[2];
  #pragma unroll
  for (int c = 0; c < 2; ++c) {
    const float* src = Qg + ((size_t)(b * Sn + qrow)) * Dn + 32 * c + 8 * g;
    float a8[8];
    *(float4*)&a8[0] = *(const float4*)src;
    *(float4*)&a8[4] = *(const float4*)(src + 4);
    #pragma unroll
    for (int j = 0; j < 8; ++j) a8[j] *= SCALE2;
    cvt8(a8, qh[c], ql[c]);
  }

  f32x4 accO[4];
  #pragma unroll
  for (int ds = 0; ds < 4; ++ds) accO[ds] = {0.f, 0.f, 0.f, 0.f};

  // DMA one 16KB blob: 16 x 1KB chunks over 8 waves (2 cp16 each).
  auto load_kv = [&](int bb, int kt) {
    const half_t* src = KVW + ((size_t)(b * NKT + kt)) * 8192;
    half_t* dst = KV_s[bb];
    cp16(dst + w * 512, src + w * 512 + lane * 8);
    cp16(dst + 4096 + w * 512, src + 4096 + w * 512 + lane * 8);
  };

  // Per-thread loop-invariant LDS offsets (halfs) and lg2inv pointer.
  const int krow = 16 * wk + c16;
  const int okh0 = swz_k(krow, 8 * g);
  const int okh1 = swz_k(krow, 32 + 8 * g);
  const float* lgp = lg2inv + (size_t)b * Sn + 16 * wk + 4 * g;

  load_kv(0, 0);
  __syncthreads();
  for (int kt = 0; kt < NKT; ++kt) {
    if (kt + 1 < NKT) load_kv((kt + 1) & 1, kt + 1);
    const int cur = kt & 1;
    const half_t* KH = &KV_s[cur][0];
    const half_t* VT = &KV_s[cur][4096];

    half8 kh0 = *(const half8*)&KH[okh0];
    half8 kh1 = *(const half8*)&KH[okh1];
    f32x4 lg4 = *(const f32x4*)(lgp + (size_t)kt * 64);  // L1/L2-resident

    __builtin_amdgcn_s_setprio(1);
    f32x4 acc = lg4;  // C-in fold: result = s' + lg
    acc = MFMA32(kh0, qh[0], acc);
    acc = MFMA32(kh1, qh[1], acc);
    acc = MFMA32(kh0, ql[0], acc);
    acc = MFMA32(kh1, ql[1], acc);
    __builtin_amdgcn_s_setprio(0);

    half4 ph = {(half_t)fexp2(acc[0]), (half_t)fexp2(acc[1]),
                (half_t)fexp2(acc[2]), (half_t)fexp2(acc[3])};

    __builtin_amdgcn_s_setprio(1);
    #pragma unroll
    for (int ds = 0; ds < 4; ++ds) {
      half4 vt = *(const half4*)&VT[swz_v(16 * ds + c16, 16 * wk + 4 * g)];
      accO[ds] = MFMA16(vt, ph, accO[ds]);
    }
    __builtin_amdgcn_s_setprio(0);

    __syncthreads();
  }

  // ---- wk(4)-reduction via staging-LDS reuse ----
  // Slots: (wq[2] x (wk-1)[3] x ds[4]) x 256 floats = 6144 floats = 24KB
  // (KV_s total 32KB — fits).
  float* red = (float*)&KV_s[0][0];
  if (wk != 0) {
    #pragma unroll
    for (int ds = 0; ds < 4; ++ds)
      *(f32x4*)&red[(((wq * 3 + (wk - 1)) * 4) + ds) * 256 + lane * 4] = accO[ds];
  }
  __syncthreads();
  if (wk == 0) {
    float* Ob = Og + ((size_t)(b * Sn + qrow)) * Dn;
    #pragma unroll
    for (int ds = 0; ds < 4; ++ds) {
      f32x4 o = accO[ds];
      #pragma unroll
      for (int j = 0; j < 3; ++j)
        o += *(const f32x4*)&red[(((wq * 3 + j) * 4) + ds) * 256 + lane * 4];
      *(f32x4*)(Ob + 16 * ds + 4 * g) = o;
    }
  }
}

// ===========================================================================
// FALLBACK PATH (round-3 kernels, needs only 128 KB ws).
// ===========================================================================
__global__ __launch_bounds__(256, 2)
void fb_attn_linv(const float* __restrict__ Kg, const float* __restrict__ Qg,
                  float* __restrict__ linv) {
  __shared__ alignas(16) half_t Qh_s[128 * 64];
  __shared__ alignas(16) half_t Ql_s[128 * 64];
  __shared__ alignas(16) float red[4][4][16];

  const int t = threadIdx.x;
  const int lane = t & 63, w = t >> 6, g = lane >> 4, c16 = lane & 15;
  const int b = blockIdx.y;
  const int k0 = blockIdx.x * 64;

  half8 kfh[4][2], kfl[4][2];
  #pragma unroll
  for (int ks = 0; ks < 4; ++ks)
    #pragma unroll
    for (int c = 0; c < 2; ++c) {
      const float* src = Kg + ((size_t)(b * Sn + k0 + 16 * ks + c16)) * Dn + 32 * c + 8 * g;
      float a8[8];
      *(float4*)&a8[0] = *(const float4*)src;
      *(float4*)&a8[4] = *(const float4*)(src + 4);
      cvt8(a8, kfh[ks][c], kfl[ks][c]);
    }

  float lsum[4] = {0.f, 0.f, 0.f, 0.f};

  for (int q0 = 0; q0 < Sn; q0 += 128) {
    __syncthreads();
    const float* Qb = Qg + ((size_t)(b * Sn + q0)) * Dn;
    #pragma unroll
    for (int i = 0; i < 8; ++i) {
      int f = t + 256 * i, q = f >> 4, d4 = (f & 15) << 2;
      float4 v = *(const float4*)(Qb + (size_t)q * Dn + d4);
      float s4[4] = {v.x * SCALE, v.y * SCALE, v.z * SCALE, v.w * SCALE};
      half4 h, l;
      #pragma unroll
      for (int j = 0; j < 4; ++j) {
        half_t hh = (half_t)s4[j];
        h[j] = hh;
        l[j] = (half_t)(s4[j] - (float)hh);
      }
      *(half4*)&Qh_s[swz_k(q, d4)] = h;
      *(half4*)&Ql_s[swz_k(q, d4)] = l;
    }
    __syncthreads();

    #pragma unroll
    for (int qs = 0; qs < 2; ++qs) {
      const int qloc = 32 * w + 16 * qs + c16;
      half8 qh[2], ql[2];
      #pragma unroll
      for (int c = 0; c < 2; ++c) {
        qh[c] = *(const half8*)&Qh_s[swz_k(qloc, 32 * c + 8 * g)];
        ql[c] = *(const half8*)&Ql_s[swz_k(qloc, 32 * c + 8 * g)];
      }
      #pragma unroll
      for (int ks = 0; ks < 4; ++ks) {
        f32x4 acc = {0.f, 0.f, 0.f, 0.f};
        acc = MFMA32(qh[0], kfh[ks][0], acc);
        acc = MFMA32(qh[1], kfh[ks][1], acc);
        acc = MFMA32(ql[0], kfh[ks][0], acc);
        acc = MFMA32(ql[1], kfh[ks][1], acc);
        acc = MFMA32(qh[0], kfl[ks][0], acc);
        acc = MFMA32(qh[1], kfl[ks][1], acc);
        lsum[ks] += __expf(acc[0]) + __expf(acc[1]) + __expf(acc[2]) + __expf(acc[3]);
      }
    }
  }

  #pragma unroll
  for (int ks = 0; ks < 4; ++ks) {
    lsum[ks] += __shfl_xor(lsum[ks], 16);
    lsum[ks] += __shfl_xor(lsum[ks], 32);
  }
  __syncthreads();
  if (lane < 16) {
    #pragma unroll
    for (int ks = 0; ks < 4; ++ks) red[w][ks][lane] = lsum[ks];
  }
  __syncthreads();
  if (t < 64) {
    int ks = t >> 4, c = t & 15;
    float tot = red[0][ks][c] + red[1][ks][c] + red[2][ks][c] + red[3][ks][c];
    linv[(size_t)b * Sn + k0 + 16 * ks + c] = 1.0f / tot;
  }
}

__global__ __launch_bounds__(512, 2)
void fb_attn_pv(const float* __restrict__ Vg, const float* __restrict__ Kg,
                const float* __restrict__ Qg, const float* __restrict__ linv,
                float* __restrict__ Og) {
  __shared__ alignas(16) half_t Kh_s[64 * 64];
  __shared__ alignas(16) half_t Kl_s[64 * 64];
  __shared__ alignas(16) half_t Vt_s[64 * 64];
  __shared__ alignas(16) float li_s[64];
  __shared__ alignas(16) float red[4][2][4][256];

  const int t = threadIdx.x;
  const int lane = t & 63, w = t >> 6;
  const int g = (lane >> 4) & 3, c16 = lane & 15;
  const int wq = w & 3, wk = w >> 2;
  const int b = blockIdx.y;
  const int q0 = blockIdx.x * 128;

  half8 qh[2][2], ql[2][2];
  #pragma unroll
  for (int qs = 0; qs < 2; ++qs) {
    const int qrow = q0 + 32 * wq + 16 * qs + c16;
    #pragma unroll
    for (int c = 0; c < 2; ++c) {
      const float* src = Qg + ((size_t)(b * Sn + qrow)) * Dn + 32 * c + 8 * g;
      float a8[8];
      *(float4*)&a8[0] = *(const float4*)src;
      *(float4*)&a8[4] = *(const float4*)(src + 4);
      #pragma unroll
      for (int j = 0; j < 8; ++j) a8[j] *= SCALE;
      cvt8(a8, qh[qs][c], ql[qs][c]);
    }
  }

  f32x4 accO[2][4];
  #pragma unroll
  for (int qs = 0; qs < 2; ++qs)
    #pragma unroll
    for (int ds = 0; ds < 4; ++ds) accO[qs][ds] = {0.f, 0.f, 0.f, 0.f};

  const int krow0 = t >> 4, kd40 = (t & 15) << 2;
  const int krow1 = 32 + (t >> 4), kd41 = kd40;
  const int vk2 = t >> 4, vdg = t & 15;

  float4 kreg0, kreg1, vreg0, vreg1;
  float li_reg = 0.f;
  {
    const float* Kb = Kg + ((size_t)(b * Sn)) * Dn;
    const float* Vb = Vg + ((size_t)(b * Sn)) * Dn;
    kreg0 = *(const float4*)(Kb + (size_t)krow0 * Dn + kd40);
    kreg1 = *(const float4*)(Kb + (size_t)krow1 * Dn + kd41);
    vreg0 = *(const float4*)(Vb + (size_t)(2 * vk2) * Dn + 4 * vdg);
    vreg1 = *(const float4*)(Vb + (size_t)(2 * vk2 + 1) * Dn + 4 * vdg);
    if (t < 64) li_reg = linv[(size_t)b * Sn + t];
  }

  for (int kt = 0; kt < Sn / 64; ++kt) {
    __syncthreads();
    {
      const float* k0p = (const float*)&kreg0;
      const float* k1p = (const float*)&kreg1;
      half4 h, l;
      #pragma unroll
      for (int j = 0; j < 4; ++j) {
        half_t hh = (half_t)k0p[j];
        h[j] = hh; l[j] = (half_t)(k0p[j] - (float)hh);
      }
      *(half4*)&Kh_s[swz_k(krow0, kd40)] = h;
      *(half4*)&Kl_s[swz_k(krow0, kd40)] = l;
      #pragma unroll
      for (int j = 0; j < 4; ++j) {
        half_t hh = (half_t)k1p[j];
        h[j] = hh; l[j] = (half_t)(k1p[j] - (float)hh);
      }
      *(half4*)&Kh_s[swz_k(krow1, kd41)] = h;
      *(half4*)&Kl_s[swz_k(krow1, kd41)] = l;

      const float* v0p = (const float*)&vreg0;
      const float* v1p = (const float*)&vreg1;
      #pragma unroll
      for (int j = 0; j < 4; ++j) {
        half2v pair = {(half_t)v0p[j], (half_t)v1p[j]};
        *(half2v*)&Vt_s[swz_v(4 * vdg + j, 2 * vk2)] = pair;
      }
      if (t < 64) li_s[t] = li_reg;
    }
    __syncthreads();

    if (kt + 1 < Sn / 64) {
      const float* Kb = Kg + ((size_t)(b * Sn + (kt + 1) * 64)) * Dn;
      const float* Vb = Vg + ((size_t)(b * Sn + (kt + 1) * 64)) * Dn;
      kreg0 = *(const float4*)(Kb + (size_t)krow0 * Dn + kd40);
      kreg1 = *(const float4*)(Kb + (size_t)krow1 * Dn + kd41);
      vreg0 = *(const float4*)(Vb + (size_t)(2 * vk2) * Dn + 4 * vdg);
      vreg1 = *(const float4*)(Vb + (size_t)(2 * vk2 + 1) * Dn + 4 * vdg);
      if (t < 64) li_reg = linv[(size_t)b * Sn + (kt + 1) * 64 + t];
    }

    #pragma unroll
    for (int kss = 0; kss < 2; ++kss) {
      const int ks = 2 * wk + kss;
      const int krow = 16 * ks + c16;
      half8 kh0 = *(const half8*)&Kh_s[swz_k(krow, 8 * g)];
      half8 kh1 = *(const half8*)&Kh_s[swz_k(krow, 32 + 8 * g)];
      half8 kl0 = *(const half8*)&Kl_s[swz_k(krow, 8 * g)];
      half8 kl1 = *(const half8*)&Kl_s[swz_k(krow, 32 + 8 * g)];
      f32x4 li4 = *(const f32x4*)&li_s[16 * ks + 4 * g];

      half4 ph[2];
      #pragma unroll
      for (int qs = 0; qs < 2; ++qs) {
        f32x4 acc = {0.f, 0.f, 0.f, 0.f};
        acc = MFMA32(kh0, qh[qs][0], acc);
        acc = MFMA32(kh1, qh[qs][1], acc);
        acc = MFMA32(kh0, ql[qs][0], acc);
        acc = MFMA32(kh1, ql[qs][1], acc);
        acc = MFMA32(kl0, qh[qs][0], acc);
        acc = MFMA32(kl1, qh[qs][1], acc);
        float p0 = __expf(acc[0]) * li4[0];
        float p1 = __expf(acc[1]) * li4[1];
        float p2 = __expf(acc[2]) * li4[2];
        float p3 = __expf(acc[3]) * li4[3];
        ph[qs] = {(half_t)p0, (half_t)p1, (half_t)p2, (half_t)p3};
      }
      #pragma unroll
      for (int ds = 0; ds < 4; ++ds) {
        half4 vt = *(const half4*)&Vt_s[swz_v(16 * ds + c16, 16 * ks + 4 * g)];
        accO[0][ds] = MFMA16(vt, ph[0], accO[0][ds]);
        accO[1][ds] = MFMA16(vt, ph[1], accO[1][ds]);
      }
    }
  }

  if (wk == 1) {
    #pragma unroll
    for (int qs = 0; qs < 2; ++qs)
      #pragma unroll
      for (int ds = 0; ds < 4; ++ds)
        *(f32x4*)&red[wq][qs][ds][lane * 4] = accO[qs][ds];
  }
  __syncthreads();
  if (wk == 0) {
    #pragma unroll
    for (int qs = 0; qs < 2; ++qs) {
      const int qrow = q0 + 32 * wq + 16 * qs + c16;
      float* Ob = Og + ((size_t)(b * Sn + qrow)) * Dn;
      #pragma unroll
      for (int ds = 0; ds < 4; ++ds) {
        f32x4 o = accO[qs][ds] + *(const f32x4*)&red[wq][qs][ds][lane * 4];
        *(f32x4*)(Ob + 16 * ds + 4 * g) = o;
      }
    }
  }
}

extern "C" void kernel_launch(void* const* d_in, const int* in_sizes, int n_in,
                              void* d_out, int out_size, void* d_ws, size_t ws_size,
                              hipStream_t stream) {
  const float* V = reinterpret_cast<const float*>(d_in[0]);
  const float* K = reinterpret_cast<const float*>(d_in[1]);
  const float* Q = reinterpret_cast<const float*>(d_in[2]);
  float* O = reinterpret_cast<float*>(d_out);

  char* ws = reinterpret_cast<char*>(d_ws);
  const size_t MB = 1024 * 1024;
  const size_t WS_NEEDED = 21 * MB;

  float* li = reinterpret_cast<float*>(ws);  // 128 KB (lg2inv in fast path)
  if (ws_size >= WS_NEEDED) {
    half_t* QhW = reinterpret_cast<half_t*>(ws + 1 * MB);
    half_t* QlW = reinterpret_cast<half_t*>(ws + 5 * MB);
    half_t* KVW = reinterpret_cast<half_t*>(ws + 9 * MB);  // 8 MB
    // 1-D grids with b = id&7 so each XCD's L2 sees only one batch's ws slice.
    prep_q<<<dim3(NQT * Bn), dim3(256), 0, stream>>>(Q, QhW, QlW);
    attn_linv<<<dim3(NKT * Bn), dim3(256), 0, stream>>>(K, V, QhW, QlW, li, KVW);
    attn_pv<<<dim3((Sn / 32) * Bn), dim3(512), 0, stream>>>(KVW, Q, li, O);
  } else {
    fb_attn_linv<<<dim3(Sn / 64, Bn), dim3(256), 0, stream>>>(K, Q, li);
    fb_attn_pv<<<dim3(Sn / 128, Bn), dim3(512), 0, stream>>>(V, K, Q, li, O);
  }
}

// Round 16
// 108.549 us; speedup vs baseline: 1.1845x; 1.1845x over previous
//
#include <hip/hip_runtime.h>

#define Bn 8
#define Sn 4096
#define Dn 64

constexpr int NKT = Sn / 64;    // 64 k-tiles per batch
constexpr int NQT = Sn / 128;   // 32 q-tiles per batch (linv q-sweep)

typedef _Float16 half_t;
typedef __attribute__((ext_vector_type(2))) _Float16 half2v;
typedef __attribute__((ext_vector_type(4))) _Float16 half4;
typedef __attribute__((ext_vector_type(8))) _Float16 half8;
typedef __attribute__((ext_vector_type(4))) float f32x4;

constexpr float SCALE = 0.125f;                         // fallback path
constexpr float SCALE2 = 0.125f * 1.4426950408889634f;  // fold log2e -> exp2

#define MFMA32(a, b, c) __builtin_amdgcn_mfma_f32_16x16x32_f16((a), (b), (c), 0, 0, 0)
#define MFMA16(a, b, c) __builtin_amdgcn_mfma_f32_16x16x16f16((a), (b), (c), 0, 0, 0)

// Raw v_exp_f32 (args bounded; libm denorm fixup is dead weight).
__device__ __forceinline__ float fexp2(float x) {
#if defined(__has_builtin) && __has_builtin(__builtin_amdgcn_exp2f)
  return __builtin_amdgcn_exp2f(x);
#else
  return exp2f(x);
#endif
}

// Swizzled half-index for row-major [R][64] f16 tiles.
__device__ __forceinline__ int swz_k(int row, int col) {
  return row * 64 + (col ^ ((row & 7) << 3));
}
__device__ __forceinline__ int swz_v(int row, int col) {
  return row * 64 + (col ^ (((row & 7) << 3) ^ (((row >> 3) & 7) << 2)));
}

// f32 -> f16 hi + f16 lo (x ~= h + l, err ~2^-22|x|)
__device__ __forceinline__ void cvt8(const float* s, half8& h, half8& l) {
  #pragma unroll
  for (int j = 0; j < 8; ++j) {
    half_t hh = (half_t)s[j];
    h[j] = hh;
    l[j] = (half_t)(s[j] - (float)hh);
  }
}

// Async global->LDS 16B per lane: lds base must be wave-uniform.
__device__ __forceinline__ void cp16(half_t* lds, const half_t* g) {
  __builtin_amdgcn_global_load_lds(
      (const __attribute__((address_space(1))) unsigned int*)g,
      (__attribute__((address_space(3))) unsigned int*)lds, 16, 0, 0);
}

// ===========================================================================
// FAST PATH (needs ~21 MB of d_ws) — ROUND-14 CONFIGURATION (measured best:
// total 108.7 us; pv 66.6, MfmaUtil 44 + VALUBusy 40 ~ 84% issue-slot).
// Occupancy sweep complete: 2 blocks/CU x 2-qs waves is the optimum
// (r15: 4 blocks/CU thin waves = +26% staging overhead; r9: 1 block/CU
// = -10%). Pipelining (r12), barrier-free (r13), reg-streaming (r10) all
// tested and rejected.
// ws layout: li (128KB @0) | QhW (4MB @1MB) | QlW (4MB @5MB) | KVW (8MB @9MB)
// KVW per k-tile blob (8192 halfs): [0,4096) Kh (swz_k) | [4096,8192) Vt (swz_v)
// 2-term QK (kh*qh + kh*ql) in BOTH linv and pv: normalization exact w.r.t.
// the shared approximation s^ = q . f16(K) (validated r14: absmax unchanged).
// ===========================================================================

// ---------------------------------------------------------------------------
// prep_q: Q (f32) -> QhW/QlW (f16 hi/lo, scaled by SCALE2, swz_k layout).
// ---------------------------------------------------------------------------
__global__ __launch_bounds__(256, 2)
void prep_q(const float* __restrict__ Qg, half_t* __restrict__ QhW,
            half_t* __restrict__ QlW) {
  const int t = threadIdx.x;
  const int b = blockIdx.x & 7, qt = blockIdx.x >> 3;
  const float* Qb = Qg + ((size_t)(b * Sn + qt * 128)) * Dn;
  half_t* qh = QhW + ((size_t)(b * NQT + qt)) * 8192;
  half_t* ql = QlW + ((size_t)(b * NQT + qt)) * 8192;
  #pragma unroll
  for (int i = 0; i < 8; ++i) {
    int f = t + 256 * i, q = f >> 4, d4 = (f & 15) << 2;
    float4 v = *(const float4*)(Qb + (size_t)q * Dn + d4);
    float s4[4] = {v.x * SCALE2, v.y * SCALE2, v.z * SCALE2, v.w * SCALE2};
    half4 h, l;
    #pragma unroll
    for (int j = 0; j < 4; ++j) {
      half_t hh = (half_t)s4[j];
      h[j] = hh;
      l[j] = (half_t)(s4[j] - (float)hh);
    }
    *(half4*)&qh[swz_k(q, d4)] = h;
    *(half4*)&ql[swz_k(q, d4)] = l;
  }
}

// ---------------------------------------------------------------------------
// attn_linv: lg2inv[b,k] = -log2(sum_q exp2(s^'[q,k])) + fused K/V prep into
// the KVW blob (Kh + Vt only). 256 thr / (256,2). Rule #20: prep write uses
// compile-time `if (ks == w)` indexing (runtime kfh[w] -> scratch, 5x).
// ---------------------------------------------------------------------------
__global__ __launch_bounds__(256, 2)
void attn_linv(const float* __restrict__ Kg, const float* __restrict__ Vg,
               const half_t* __restrict__ QhW, const half_t* __restrict__ QlW,
               float* __restrict__ lg2inv, half_t* __restrict__ KVW) {
  __shared__ alignas(16) half_t Qh_s[2][8192];   // 2 x 16KB
  __shared__ alignas(16) half_t Ql_s[2][8192];   // 2 x 16KB
  __shared__ alignas(16) float red[4][4][16];

  const int t = threadIdx.x;
  const int lane = t & 63, w = t >> 6, g = lane >> 4, c16 = lane & 15;
  const int b = blockIdx.x & 7, kx = blockIdx.x >> 3;
  const int k0 = kx * 64;

  half_t* blob = KVW + ((size_t)(b * NKT + kx)) * 8192;

  // --- K hi fragments (registers) + one-time prep write into blob ---
  half8 kfh[4][2];
  #pragma unroll
  for (int ks = 0; ks < 4; ++ks)
    #pragma unroll
    for (int c = 0; c < 2; ++c) {
      const float* src = Kg + ((size_t)(b * Sn + k0 + 16 * ks + c16)) * Dn + 32 * c + 8 * g;
      float a8[8];
      *(float4*)&a8[0] = *(const float4*)src;
      *(float4*)&a8[4] = *(const float4*)(src + 4);
      #pragma unroll
      for (int j = 0; j < 8; ++j) kfh[ks][c][j] = (half_t)a8[j];
    }
  {
    #pragma unroll
    for (int ks = 0; ks < 4; ++ks)
      if (ks == w) {  // compile-time ks index under predication — no scratch
        #pragma unroll
        for (int c = 0; c < 2; ++c)
          *(half8*)&blob[swz_k(16 * ks + c16, 32 * c + 8 * g)] = kfh[ks][c];
      }
  }
  // --- one-time V transpose prep into blob[4096..] ---
  {
    const float* Vb = Vg + ((size_t)(b * Sn + k0)) * Dn;
    #pragma unroll
    for (int i = 0; i < 2; ++i) {
      int u = t + 256 * i;
      int k2 = u >> 4, dg = u & 15;
      float4 v0 = *(const float4*)(Vb + (size_t)(2 * k2) * Dn + 4 * dg);
      float4 v1 = *(const float4*)(Vb + (size_t)(2 * k2 + 1) * Dn + 4 * dg);
      const float* v0p = (const float*)&v0;
      const float* v1p = (const float*)&v1;
      #pragma unroll
      for (int j = 0; j < 4; ++j) {
        half2v pair = {(half_t)v0p[j], (half_t)v1p[j]};
        *(half2v*)&blob[4096 + swz_v(4 * dg + j, 2 * k2)] = pair;
      }
    }
  }

  const half_t* qhw = QhW + (size_t)b * NQT * 8192;
  const half_t* qlw = QlW + (size_t)b * NQT * 8192;

  // DMA one 128-q tile (16KB per array): 4 chunks/wave/array.
  auto load_q = [&](int bb, int qt) {
    const size_t toff = (size_t)qt * 8192;
    #pragma unroll
    for (int c = 0; c < 4; ++c) {
      const int ch = (c * 4 + w) * 512;  // halfs
      cp16(&Qh_s[bb][ch], qhw + toff + ch + lane * 8);
      cp16(&Ql_s[bb][ch], qlw + toff + ch + lane * 8);
    }
  };

  float lsum[4] = {0.f, 0.f, 0.f, 0.f};

  load_q(0, 0);
  __syncthreads();
  for (int qt = 0; qt < NQT; ++qt) {
    if (qt + 1 < NQT) load_q((qt + 1) & 1, qt + 1);
    const int cur = qt & 1;
    #pragma unroll
    for (int qs = 0; qs < 2; ++qs) {
      const int qloc = 32 * w + 16 * qs + c16;
      half8 qh[2], ql[2];
      #pragma unroll
      for (int c = 0; c < 2; ++c) {
        qh[c] = *(const half8*)&Qh_s[cur][swz_k(qloc, 32 * c + 8 * g)];
        ql[c] = *(const half8*)&Ql_s[cur][swz_k(qloc, 32 * c + 8 * g)];
      }
      #pragma unroll
      for (int ks = 0; ks < 4; ++ks) {
        f32x4 acc = {0.f, 0.f, 0.f, 0.f};
        acc = MFMA32(qh[0], kfh[ks][0], acc);
        acc = MFMA32(qh[1], kfh[ks][1], acc);
        acc = MFMA32(ql[0], kfh[ks][0], acc);
        acc = MFMA32(ql[1], kfh[ks][1], acc);
        lsum[ks] += fexp2(acc[0]) + fexp2(acc[1]) + fexp2(acc[2]) + fexp2(acc[3]);
      }
    }
    __syncthreads();
  }

  // lane (c16,g) holds partials for column k = k0+16ks+c16 over its q rows
  #pragma unroll
  for (int ks = 0; ks < 4; ++ks) {
    lsum[ks] += __shfl_xor(lsum[ks], 16);
    lsum[ks] += __shfl_xor(lsum[ks], 32);
  }
  __syncthreads();
  if (lane < 16) {
    #pragma unroll
    for (int ks = 0; ks < 4; ++ks) red[w][ks][lane] = lsum[ks];
  }
  __syncthreads();
  if (t < 64) {
    int ks = t >> 4, c = t & 15;
    float tot = red[0][ks][c] + red[1][ks][c] + red[2][ks][c] + red[3][ks][c];
    lg2inv[(size_t)b * Sn + k0 + 16 * ks + c] = -log2f(tot);
  }
}

// ---------------------------------------------------------------------------
// attn_pv: O[q,d] = sum_k exp2(s^' + lg2inv[k]) * V[k,d].
// Measured-best structure: 512 thr (8 waves), q-tile 64, grid 512 -> 2
// blocks/CU, LDS double-buffer + per-tile __syncthreads; lg folded into the
// MFMA C-input; 2-term QK (4 MFMA32 per qs); blob 16KB/tile, LDS 32KB.
// ---------------------------------------------------------------------------
__global__ __launch_bounds__(512, 4)
void attn_pv(const half_t* __restrict__ KVW, const float* __restrict__ Qg,
             const float* __restrict__ lg2inv, float* __restrict__ Og) {
  __shared__ alignas(16) half_t KV_s[2][8192];  // [Kh 8KB | Vt 8KB] per buffer

  const int t = threadIdx.x;
  const int lane = t & 63, w = t >> 6;  // 8 waves
  const int g = (lane >> 4) & 3, c16 = lane & 15;
  const int wk = w & 3, wq = w >> 2;    // wq in {0,1}
  const int b = blockIdx.x & 7;
  const int q0 = (blockIdx.x >> 3) * 64;

  // Resident Q fragments: 2 qs x 2 halves, hi/lo, scaled by SCALE2.
  half8 qh[2][2], ql[2][2];
  #pragma unroll
  for (int qs = 0; qs < 2; ++qs) {
    const int qrow = q0 + 32 * wq + 16 * qs + c16;
    #pragma unroll
    for (int c = 0; c < 2; ++c) {
      const float* src = Qg + ((size_t)(b * Sn + qrow)) * Dn + 32 * c + 8 * g;
      float a8[8];
      *(float4*)&a8[0] = *(const float4*)src;
      *(float4*)&a8[4] = *(const float4*)(src + 4);
      #pragma unroll
      for (int j = 0; j < 8; ++j) a8[j] *= SCALE2;
      cvt8(a8, qh[qs][c], ql[qs][c]);
    }
  }

  f32x4 accO[2][4];
  #pragma unroll
  for (int qs = 0; qs < 2; ++qs)
    #pragma unroll
    for (int ds = 0; ds < 4; ++ds) accO[qs][ds] = {0.f, 0.f, 0.f, 0.f};

  // DMA one 16KB blob: 16 x 1KB chunks over 8 waves (2 cp16 each).
  auto load_kv = [&](int bb, int kt) {
    const half_t* src = KVW + ((size_t)(b * NKT + kt)) * 8192;
    half_t* dst = KV_s[bb];
    cp16(dst + w * 512, src + w * 512 + lane * 8);
    cp16(dst + 4096 + w * 512, src + 4096 + w * 512 + lane * 8);
  };

  // Per-thread loop-invariant LDS offsets (halfs) and lg2inv pointer.
  const int krow = 16 * wk + c16;
  const int okh0 = swz_k(krow, 8 * g);
  const int okh1 = swz_k(krow, 32 + 8 * g);
  const float* lgp = lg2inv + (size_t)b * Sn + 16 * wk + 4 * g;

  load_kv(0, 0);
  __syncthreads();
  for (int kt = 0; kt < NKT; ++kt) {
    if (kt + 1 < NKT) load_kv((kt + 1) & 1, kt + 1);
    const int cur = kt & 1;
    const half_t* KH = &KV_s[cur][0];
    const half_t* VT = &KV_s[cur][4096];

    half8 kh0 = *(const half8*)&KH[okh0];
    half8 kh1 = *(const half8*)&KH[okh1];
    f32x4 lg4 = *(const f32x4*)(lgp + (size_t)kt * 64);  // L1-resident

    f32x4 sv[2];
    __builtin_amdgcn_s_setprio(1);
    #pragma unroll
    for (int qs = 0; qs < 2; ++qs) {
      f32x4 acc = lg4;  // C-in fold: result = s' + lg, no separate adds
      acc = MFMA32(kh0, qh[qs][0], acc);
      acc = MFMA32(kh1, qh[qs][1], acc);
      acc = MFMA32(kh0, ql[qs][0], acc);
      acc = MFMA32(kh1, ql[qs][1], acc);
      sv[qs] = acc;
    }
    __builtin_amdgcn_s_setprio(0);

    half4 ph[2];
    #pragma unroll
    for (int qs = 0; qs < 2; ++qs) {
      float p0 = fexp2(sv[qs][0]);
      float p1 = fexp2(sv[qs][1]);
      float p2 = fexp2(sv[qs][2]);
      float p3 = fexp2(sv[qs][3]);
      ph[qs] = {(half_t)p0, (half_t)p1, (half_t)p2, (half_t)p3};
    }

    __builtin_amdgcn_s_setprio(1);
    #pragma unroll
    for (int ds = 0; ds < 4; ++ds) {
      half4 vt = *(const half4*)&VT[swz_v(16 * ds + c16, 16 * wk + 4 * g)];
      accO[0][ds] = MFMA16(vt, ph[0], accO[0][ds]);
      accO[1][ds] = MFMA16(vt, ph[1], accO[1][ds]);
    }
    __builtin_amdgcn_s_setprio(0);

    __syncthreads();
  }

  // ---- wk(4)-reduction via staging-LDS reuse: one qs per round ----
  // Slots: (wq[2] x (wk-1)[3] x ds[4]) x 256 floats = 6144 floats = 24KB
  // (KV_s total 32KB = 8192 floats — fits).
  float* red = (float*)&KV_s[0][0];
  #pragma unroll
  for (int qs = 0; qs < 2; ++qs) {
    if (wk != 0) {
      #pragma unroll
      for (int ds = 0; ds < 4; ++ds)
        *(f32x4*)&red[(((wq * 3 + (wk - 1)) * 4) + ds) * 256 + lane * 4] = accO[qs][ds];
    }
    __syncthreads();
    if (wk == 0) {
      const int qrow = q0 + 32 * wq + 16 * qs + c16;
      float* Ob = Og + ((size_t)(b * Sn + qrow)) * Dn;
      #pragma unroll
      for (int ds = 0; ds < 4; ++ds) {
        f32x4 o = accO[qs][ds];
        #pragma unroll
        for (int j = 0; j < 3; ++j)
          o += *(const f32x4*)&red[(((wq * 3 + j) * 4) + ds) * 256 + lane * 4];
        *(f32x4*)(Ob + 16 * ds + 4 * g) = o;
      }
    }
    __syncthreads();
  }
}

// ===========================================================================
// FALLBACK PATH (round-3 kernels, needs only 128 KB ws).
// ===========================================================================
__global__ __launch_bounds__(256, 2)
void fb_attn_linv(const float* __restrict__ Kg, const float* __restrict__ Qg,
                  float* __restrict__ linv) {
  __shared__ alignas(16) half_t Qh_s[128 * 64];
  __shared__ alignas(16) half_t Ql_s[128 * 64];
  __shared__ alignas(16) float red[4][4][16];

  const int t = threadIdx.x;
  const int lane = t & 63, w = t >> 6, g = lane >> 4, c16 = lane & 15;
  const int b = blockIdx.y;
  const int k0 = blockIdx.x * 64;

  half8 kfh[4][2], kfl[4][2];
  #pragma unroll
  for (int ks = 0; ks < 4; ++ks)
    #pragma unroll
    for (int c = 0; c < 2; ++c) {
      const float* src = Kg + ((size_t)(b * Sn + k0 + 16 * ks + c16)) * Dn + 32 * c + 8 * g;
      float a8[8];
      *(float4*)&a8[0] = *(const float4*)src;
      *(float4*)&a8[4] = *(const float4*)(src + 4);
      cvt8(a8, kfh[ks][c], kfl[ks][c]);
    }

  float lsum[4] = {0.f, 0.f, 0.f, 0.f};

  for (int q0 = 0; q0 < Sn; q0 += 128) {
    __syncthreads();
    const float* Qb = Qg + ((size_t)(b * Sn + q0)) * Dn;
    #pragma unroll
    for (int i = 0; i < 8; ++i) {
      int f = t + 256 * i, q = f >> 4, d4 = (f & 15) << 2;
      float4 v = *(const float4*)(Qb + (size_t)q * Dn + d4);
      float s4[4] = {v.x * SCALE, v.y * SCALE, v.z * SCALE, v.w * SCALE};
      half4 h, l;
      #pragma unroll
      for (int j = 0; j < 4; ++j) {
        half_t hh = (half_t)s4[j];
        h[j] = hh;
        l[j] = (half_t)(s4[j] - (float)hh);
      }
      *(half4*)&Qh_s[swz_k(q, d4)] = h;
      *(half4*)&Ql_s[swz_k(q, d4)] = l;
    }
    __syncthreads();

    #pragma unroll
    for (int qs = 0; qs < 2; ++qs) {
      const int qloc = 32 * w + 16 * qs + c16;
      half8 qh[2], ql[2];
      #pragma unroll
      for (int c = 0; c < 2; ++c) {
        qh[c] = *(const half8*)&Qh_s[swz_k(qloc, 32 * c + 8 * g)];
        ql[c] = *(const half8*)&Ql_s[swz_k(qloc, 32 * c + 8 * g)];
      }
      #pragma unroll
      for (int ks = 0; ks < 4; ++ks) {
        f32x4 acc = {0.f, 0.f, 0.f, 0.f};
        acc = MFMA32(qh[0], kfh[ks][0], acc);
        acc = MFMA32(qh[1], kfh[ks][1], acc);
        acc = MFMA32(ql[0], kfh[ks][0], acc);
        acc = MFMA32(ql[1], kfh[ks][1], acc);
        acc = MFMA32(qh[0], kfl[ks][0], acc);
        acc = MFMA32(qh[1], kfl[ks][1], acc);
        lsum[ks] += __expf(acc[0]) + __expf(acc[1]) + __expf(acc[2]) + __expf(acc[3]);
      }
    }
  }

  #pragma unroll
  for (int ks = 0; ks < 4; ++ks) {
    lsum[ks] += __shfl_xor(lsum[ks], 16);
    lsum[ks] += __shfl_xor(lsum[ks], 32);
  }
  __syncthreads();
  if (lane < 16) {
    #pragma unroll
    for (int ks = 0; ks < 4; ++ks) red[w][ks][lane] = lsum[ks];
  }
  __syncthreads();
  if (t < 64) {
    int ks = t >> 4, c = t & 15;
    float tot = red[0][ks][c] + red[1][ks][c] + red[2][ks][c] + red[3][ks][c];
    linv[(size_t)b * Sn + k0 + 16 * ks + c] = 1.0f / tot;
  }
}

__global__ __launch_bounds__(512, 2)
void fb_attn_pv(const float* __restrict__ Vg, const float* __restrict__ Kg,
                const float* __restrict__ Qg, const float* __restrict__ linv,
                float* __restrict__ Og) {
  __shared__ alignas(16) half_t Kh_s[64 * 64];
  __shared__ alignas(16) half_t Kl_s[64 * 64];
  __shared__ alignas(16) half_t Vt_s[64 * 64];
  __shared__ alignas(16) float li_s[64];
  __shared__ alignas(16) float red[4][2][4][256];

  const int t = threadIdx.x;
  const int lane = t & 63, w = t >> 6;
  const int g = (lane >> 4) & 3, c16 = lane & 15;
  const int wq = w & 3, wk = w >> 2;
  const int b = blockIdx.y;
  const int q0 = blockIdx.x * 128;

  half8 qh[2][2], ql[2][2];
  #pragma unroll
  for (int qs = 0; qs < 2; ++qs) {
    const int qrow = q0 + 32 * wq + 16 * qs + c16;
    #pragma unroll
    for (int c = 0; c < 2; ++c) {
      const float* src = Qg + ((size_t)(b * Sn + qrow)) * Dn + 32 * c + 8 * g;
      float a8[8];
      *(float4*)&a8[0] = *(const float4*)src;
      *(float4*)&a8[4] = *(const float4*)(src + 4);
      #pragma unroll
      for (int j = 0; j < 8; ++j) a8[j] *= SCALE;
      cvt8(a8, qh[qs][c], ql[qs][c]);
    }
  }

  f32x4 accO[2][4];
  #pragma unroll
  for (int qs = 0; qs < 2; ++qs)
    #pragma unroll
    for (int ds = 0; ds < 4; ++ds) accO[qs][ds] = {0.f, 0.f, 0.f, 0.f};

  const int krow0 = t >> 4, kd40 = (t & 15) << 2;
  const int krow1 = 32 + (t >> 4), kd41 = kd40;
  const int vk2 = t >> 4, vdg = t & 15;

  float4 kreg0, kreg1, vreg0, vreg1;
  float li_reg = 0.f;
  {
    const float* Kb = Kg + ((size_t)(b * Sn)) * Dn;
    const float* Vb = Vg + ((size_t)(b * Sn)) * Dn;
    kreg0 = *(const float4*)(Kb + (size_t)krow0 * Dn + kd40);
    kreg1 = *(const float4*)(Kb + (size_t)krow1 * Dn + kd41);
    vreg0 = *(const float4*)(Vb + (size_t)(2 * vk2) * Dn + 4 * vdg);
    vreg1 = *(const float4*)(Vb + (size_t)(2 * vk2 + 1) * Dn + 4 * vdg);
    if (t < 64) li_reg = linv[(size_t)b * Sn + t];
  }

  for (int kt = 0; kt < Sn / 64; ++kt) {
    __syncthreads();
    {
      const float* k0p = (const float*)&kreg0;
      const float* k1p = (const float*)&kreg1;
      half4 h, l;
      #pragma unroll
      for (int j = 0; j < 4; ++j) {
        half_t hh = (half_t)k0p[j];
        h[j] = hh; l[j] = (half_t)(k0p[j] - (float)hh);
      }
      *(half4*)&Kh_s[swz_k(krow0, kd40)] = h;
      *(half4*)&Kl_s[swz_k(krow0, kd40)] = l;
      #pragma unroll
      for (int j = 0; j < 4; ++j) {
        half_t hh = (half_t)k1p[j];
        h[j] = hh; l[j] = (half_t)(k1p[j] - (float)hh);
      }
      *(half4*)&Kh_s[swz_k(krow1, kd41)] = h;
      *(half4*)&Kl_s[swz_k(krow1, kd41)] = l;

      const float* v0p = (const float*)&vreg0;
      const float* v1p = (const float*)&vreg1;
      #pragma unroll
      for (int j = 0; j < 4; ++j) {
        half2v pair = {(half_t)v0p[j], (half_t)v1p[j]};
        *(half2v*)&Vt_s[swz_v(4 * vdg + j, 2 * vk2)] = pair;
      }
      if (t < 64) li_s[t] = li_reg;
    }
    __syncthreads();

    if (kt + 1 < Sn / 64) {
      const float* Kb = Kg + ((size_t)(b * Sn + (kt + 1) * 64)) * Dn;
      const float* Vb = Vg + ((size_t)(b * Sn + (kt + 1) * 64)) * Dn;
      kreg0 = *(const float4*)(Kb + (size_t)krow0 * Dn + kd40);
      kreg1 = *(const float4*)(Kb + (size_t)krow1 * Dn + kd41);
      vreg0 = *(const float4*)(Vb + (size_t)(2 * vk2) * Dn + 4 * vdg);
      vreg1 = *(const float4*)(Vb + (size_t)(2 * vk2 + 1) * Dn + 4 * vdg);
      if (t < 64) li_reg = linv[(size_t)b * Sn + (kt + 1) * 64 + t];
    }

    #pragma unroll
    for (int kss = 0; kss < 2; ++kss) {
      const int ks = 2 * wk + kss;
      const int krow = 16 * ks + c16;
      half8 kh0 = *(const half8*)&Kh_s[swz_k(krow, 8 * g)];
      half8 kh1 = *(const half8*)&Kh_s[swz_k(krow, 32 + 8 * g)];
      half8 kl0 = *(const half8*)&Kl_s[swz_k(krow, 8 * g)];
      half8 kl1 = *(const half8*)&Kl_s[swz_k(krow, 32 + 8 * g)];
      f32x4 li4 = *(const f32x4*)&li_s[16 * ks + 4 * g];

      half4 ph[2];
      #pragma unroll
      for (int qs = 0; qs < 2; ++qs) {
        f32x4 acc = {0.f, 0.f, 0.f, 0.f};
        acc = MFMA32(kh0, qh[qs][0], acc);
        acc = MFMA32(kh1, qh[qs][1], acc);
        acc = MFMA32(kh0, ql[qs][0], acc);
        acc = MFMA32(kh1, ql[qs][1], acc);
        acc = MFMA32(kl0, qh[qs][0], acc);
        acc = MFMA32(kl1, qh[qs][1], acc);
        float p0 = __expf(acc[0]) * li4[0];
        float p1 = __expf(acc[1]) * li4[1];
        float p2 = __expf(acc[2]) * li4[2];
        float p3 = __expf(acc[3]) * li4[3];
        ph[qs] = {(half_t)p0, (half_t)p1, (half_t)p2, (half_t)p3};
      }
      #pragma unroll
      for (int ds = 0; ds < 4; ++ds) {
        half4 vt = *(const half4*)&Vt_s[swz_v(16 * ds + c16, 16 * ks + 4 * g)];
        accO[0][ds] = MFMA16(vt, ph[0], accO[0][ds]);
        accO[1][ds] = MFMA16(vt, ph[1], accO[1][ds]);
      }
    }
  }

  if (wk == 1) {
    #pragma unroll
    for (int qs = 0; qs < 2; ++qs)
      #pragma unroll
      for (int ds = 0; ds < 4; ++ds)
        *(f32x4*)&red[wq][qs][ds][lane * 4] = accO[qs][ds];
  }
  __syncthreads();
  if (wk == 0) {
    #pragma unroll
    for (int qs = 0; qs < 2; ++qs) {
      const int qrow = q0 + 32 * wq + 16 * qs + c16;
      float* Ob = Og + ((size_t)(b * Sn + qrow)) * Dn;
      #pragma unroll
      for (int ds = 0; ds < 4; ++ds) {
        f32x4 o = accO[qs][ds] + *(const f32x4*)&red[wq][qs][ds][lane * 4];
        *(f32x4*)(Ob + 16 * ds + 4 * g) = o;
      }
    }
  }
}

extern "C" void kernel_launch(void* const* d_in, const int* in_sizes, int n_in,
                              void* d_out, int out_size, void* d_ws, size_t ws_size,
                              hipStream_t stream) {
  const float* V = reinterpret_cast<const float*>(d_in[0]);
  const float* K = reinterpret_cast<const float*>(d_in[1]);
  const float* Q = reinterpret_cast<const float*>(d_in[2]);
  float* O = reinterpret_cast<float*>(d_out);

  char* ws = reinterpret_cast<char*>(d_ws);
  const size_t MB = 1024 * 1024;
  const size_t WS_NEEDED = 21 * MB;

  float* li = reinterpret_cast<float*>(ws);  // 128 KB (lg2inv in fast path)
  if (ws_size >= WS_NEEDED) {
    half_t* QhW = reinterpret_cast<half_t*>(ws + 1 * MB);
    half_t* QlW = reinterpret_cast<half_t*>(ws + 5 * MB);
    half_t* KVW = reinterpret_cast<half_t*>(ws + 9 * MB);  // 8 MB
    // 1-D grids with b = id&7 so each XCD's L2 sees only one batch's ws slice.
    prep_q<<<dim3(NQT * Bn), dim3(256), 0, stream>>>(Q, QhW, QlW);
    attn_linv<<<dim3(NKT * Bn), dim3(256), 0, stream>>>(K, V, QhW, QlW, li, KVW);
    attn_pv<<<dim3((Sn / 64) * Bn), dim3(512), 0, stream>>>(KVW, Q, li, O);
  } else {
    fb_attn_linv<<<dim3(Sn / 64, Bn), dim3(256), 0, stream>>>(K, Q, li);
    fb_attn_pv<<<dim3(Sn / 128, Bn), dim3(512), 0, stream>>>(V, K, Q, li, O);
  }
}